// Round 6
// baseline (289.773 us; speedup 1.0000x reference)
//
#include <hip/hip_runtime.h>

// WARP loss: B=4096 rows, Y=10000 labels, T=128 negative-candidate trials.
// input [B,Y] f32, target [B,Y] f32 (one-hot), neg_candidates [B,T] i32.
// out[0] = sum over rows of log((Y-1)/num_trials) * (1 - s_pos + s_neg),
// num_trials = 1 + first t with 1 + s_neg_t - s_pos >= 0 (0 contribution if none).
//
// Segmented-scan design: ONE BLOCK (4 waves) PER ROW.
//   - each wave scans a 10-group (10 KB) quarter of the row in 1 KB chunks,
//     ping-pong depth-2; exactly one wave finds the one-hot and publishes the
//     element index to an LDS flag; other waves poll the flag per chunk and
//     stop within ~2 chunks  ->  expected read ~ 26 KB/row (~106 MB total),
//     worst-case serial chain 10 rounds (4x shorter than one-wave-per-row),
//     per-row finish dispersion 4x tighter (early-exit tail stays occupied).
//   - wave 0 prefetches neg + first-16 candidate gathers under the scan;
//     progressive widening (16 -> 64 -> 48 trials) since accept prob/trial
//     ~0.76 makes deeper stages ~1-2% likely. First-accept semantics exact.
//   - per-row partials in d_ws; 1-block reduce writes out[0] (overwrites
//     harness poison; no memset, no global atomics).

constexpr int Yc = 10000;
constexpr int Tc = 128;
constexpr int R4 = 2500;   // uint4 per row (40 KB, 16B-aligned per row)
constexpr int QG = 10;     // groups (1 KB = 64 lanes x uint4) per wave quarter

__global__ __launch_bounds__(256) void warp_fused_kernel(
        const float* __restrict__ input,
        const float* __restrict__ target,
        const int*   __restrict__ neg,
        float* __restrict__ partial,
        int B) {
    const int wave = threadIdx.x >> 6;
    const int lane = threadIdx.x & 63;
    const int row  = blockIdx.x;

    __shared__ int sh_pos;
    if (threadIdx.x == 0) sh_pos = -1;
    __syncthreads();
    volatile int* vpos = &sh_pos;

    if (row < B) {
        const float* irow = input + (size_t)row * Yc;
        const uint4* trow = reinterpret_cast<const uint4*>(target + (size_t)row * Yc);
        const int*   nrow = neg + row * Tc;

        auto LDG = [&](int g) -> uint4 {                 // group g, lane's uint4
            int idx = g * 64 + lane;
            return trow[idx < R4 ? idx : R4 - 1];        // clamp: same-index dup
        };

        // ---- wave-0 prologue: neg + stage-A gathers fly under the scan ----
        int   cA = 0; float sA = 0.0f;
        if (wave == 0) cA = nrow[lane & 15];             // candidates 0..15 (x4)

        const int g0 = wave * QG;                        // my quarter
        uint4 A = LDG(g0), Bv = LDG(g0 + 1);
        if (wave == 0) sA = irow[cA];

        // ---- segmented scan: check / publish / poll / refill ----
        auto CHECK1 = [&](int g, const uint4& v) -> int {
            const unsigned nz = v.x | v.y | v.z | v.w;
            if (!__any(nz != 0)) return -1;
            int mine = 0x7fffffff;
            if (nz) {
                int idx = g * 64 + lane; if (idx >= R4) idx = R4 - 1;
                int sub = v.x ? 0 : (v.y ? 1 : (v.z ? 2 : 3));
                mine = 4 * idx + sub;
            }
            #pragma unroll
            for (int off = 32; off; off >>= 1)
                mine = min(mine, __shfl_xor(mine, off));
            return mine;                                  // wave-uniform
        };

        for (int g = g0; g < g0 + QG; g += 2) {
            int f = CHECK1(g, A);                         // waits A only
            if (f >= 0) { if (lane == 0) *vpos = f; break; }
            if (*vpos >= 0) break;                        // someone else found it
            if (g + 2 < g0 + QG) A = LDG(g + 2);
            f = CHECK1(g + 1, Bv);                        // waits B only
            if (f >= 0) { if (lane == 0) *vpos = f; break; }
            if (*vpos >= 0) break;
            if (g + 3 < g0 + QG) Bv = LDG(g + 3);
        }
    }
    __syncthreads();                                      // pos published

    if (row < B && wave == 0) {
        const int   pos   = sh_pos;                       // always >= 0 (one-hot)
        const float s_pos = (pos >= 0) ? input[(size_t)row * Yc + pos] : 0.0f;
        const float* irow = input + (size_t)row * Yc;
        const int*   nrow = neg + row * Tc;
        const int    cA   = nrow[lane & 15];
        const float  sA   = irow[cA];                     // L1/L2 hit (prefetched)

        // ---- progressive first-accept: 16 -> 64 -> 48 trials ----
        int   first = -1;
        float s_neg = 0.0f;
        const unsigned long long bA =
            __ballot(1.0f + sA - s_pos >= 0.0f) & 0xFFFFull;      // trials 0..15
        if (bA) {
            first = __ffsll(bA) - 1;
            s_neg = __shfl(sA, first);
        } else {
            const int   cB = nrow[16 + lane];                     // trials 16..79
            const float sB = irow[cB];
            const unsigned long long bB = __ballot(1.0f + sB - s_pos >= 0.0f);
            if (bB) {
                const int f = __ffsll(bB) - 1;
                first = 16 + f;
                s_neg = __shfl(sB, f);
            } else {
                const int   iC = 80 + lane;                       // trials 80..127
                const int   cC = nrow[iC < Tc ? iC : Tc - 1];
                const float sC = irow[cC];
                const unsigned long long bC =
                    __ballot(1.0f + sC - s_pos >= 0.0f) & ((1ull << 48) - 1);
                if (bC) {
                    const int f = __ffsll(bC) - 1;
                    first = 80 + f;
                    s_neg = __shfl(sC, f);
                }
            }
        }

        float contrib = 0.0f;
        if (pos >= 0 && first >= 0) {
            const int   nt = first + 1;
            const float L  = logf((float)((Yc - 1) / nt));        // floor-div, log
            contrib = L * (1.0f - s_pos + s_neg);
        }
        if (lane == 0) partial[row] = contrib;
    }
}

__global__ __launch_bounds__(256) void reduce_partials(
        const float* __restrict__ partial,
        float* __restrict__ out, int n) {
    float s = 0.0f;
    for (int i = threadIdx.x; i < n; i += 256) s += partial[i];
    #pragma unroll
    for (int off = 32; off; off >>= 1) s += __shfl_down(s, off);
    __shared__ float ws[4];
    if ((threadIdx.x & 63) == 0) ws[threadIdx.x >> 6] = s;
    __syncthreads();
    if (threadIdx.x == 0) out[0] = ws[0] + ws[1] + ws[2] + ws[3];
}

extern "C" void kernel_launch(void* const* d_in, const int* in_sizes, int n_in,
                              void* d_out, int out_size, void* d_ws, size_t ws_size,
                              hipStream_t stream) {
    const float* input  = (const float*)d_in[0];
    const float* target = (const float*)d_in[1];
    const int*   neg    = (const int*)d_in[2];
    float* out     = (float*)d_out;
    float* partial = (float*)d_ws;             // B floats

    const int B = in_sizes[2] / Tc;            // 4096

    warp_fused_kernel<<<B, 256, 0, stream>>>(input, target, neg, partial, B);
    reduce_partials<<<1, 256, 0, stream>>>(partial, out, B);
}